// Round 2
// baseline (294.319 us; speedup 1.0000x reference)
//
#include <hip/hip_runtime.h>
#include <math.h>

typedef short v8s __attribute__((ext_vector_type(8)));
typedef float v4f __attribute__((ext_vector_type(4)));

#define L2E 1.4426950408889634f
#define INV_SCALE 0.08838834764831845f   // 1/sqrt(128)
#define NEG_BIG -1e30f

static __device__ __forceinline__ short f2bf(float x) {
    union { float f; unsigned u; } c; c.f = x;
    unsigned u = c.u;
    unsigned r = (u + 0x7fffu + ((u >> 16) & 1u)) >> 16;  // RNE
    return (short)r;
}

// ---------------- P0: W[256][128] f32 -> Wt[128][256] bf16 ----------------
__global__ __launch_bounds__(256) void k_wt(const float* __restrict__ Win,
                                            const float* __restrict__ Wmem,
                                            short* __restrict__ WtIn,
                                            short* __restrict__ WtMem) {
    const float* W = blockIdx.y ? Wmem : Win;
    short* Wt = blockIdx.y ? WtMem : WtIn;
    int id0 = blockIdx.x * 1024;
#pragma unroll
    for (int i = 0; i < 4; ++i) {
        int id = id0 + i * 256 + threadIdx.x;   // id = f*256 + k
        int f = id >> 8, k = id & 255;
        Wt[id] = f2bf(W[k * 128 + f]);          // coalesced writes
    }
}

// -------- P1: Y[m][128] = bf16(ELU(X[m][256] @ W)), MFMA 16x16x32 ---------
__global__ __launch_bounds__(256) void k_gemm_elu(const float* __restrict__ Xc,
                                                  const float* __restrict__ Xq,
                                                  const short* __restrict__ WtIn,
                                                  const short* __restrict__ WtMem,
                                                  short* __restrict__ Qa,
                                                  short* __restrict__ Ka) {
    const float* X = blockIdx.y ? Xq : Xc;
    const short* Wt = blockIdx.y ? WtMem : WtIn;
    short* Y = blockIdx.y ? Ka : Qa;
    int w = threadIdx.x >> 6, lane = threadIdx.x & 63;
    int ln = lane & 15, qd = lane >> 4;
    int m0 = blockIdx.x * 64 + w * 16;

    v4f zero = {0.f, 0.f, 0.f, 0.f};
    v4f o[8];
#pragma unroll
    for (int i = 0; i < 8; ++i) o[i] = zero;

#pragma unroll
    for (int kk = 0; kk < 8; ++kk) {
        // A fragment: A[m=ln][k=kk*32+qd*8+j], f32 load + cvt to bf16
        const float* xp = X + (m0 + ln) * 256 + kk * 32 + qd * 8;
        float4 x0 = *(const float4*)xp;
        float4 x1 = *(const float4*)(xp + 4);
        v8s a;
        a[0] = f2bf(x0.x); a[1] = f2bf(x0.y); a[2] = f2bf(x0.z); a[3] = f2bf(x0.w);
        a[4] = f2bf(x1.x); a[5] = f2bf(x1.y); a[6] = f2bf(x1.z); a[7] = f2bf(x1.w);
#pragma unroll
        for (int nt = 0; nt < 8; ++nt) {
            v8s b = *(const v8s*)(Wt + (nt * 16 + ln) * 256 + kk * 32 + qd * 8);
            o[nt] = __builtin_amdgcn_mfma_f32_16x16x32_bf16(a, b, o[nt], 0, 0, 0);
        }
    }
    // epilogue: ELU + bf16 store; C layout row=qd*4+r, col=ln
#pragma unroll
    for (int nt = 0; nt < 8; ++nt) {
#pragma unroll
        for (int r = 0; r < 4; ++r) {
            float v = o[nt][r];
            v = v > 0.f ? v : 0.01f * expm1f(v);
            Y[(m0 + qd * 4 + r) * 128 + nt * 16 + ln] = f2bf(v);
        }
    }
}

// ------ P2: Va_t[b][d][q] = bf16(query[b][q][d]); maskadd from qmask ------
__global__ __launch_bounds__(256) void k_vat(const float* __restrict__ Q,
                                             const int* __restrict__ qmask,
                                             short* __restrict__ VaT,
                                             float* __restrict__ maskadd) {
    __shared__ float tile[64][65];
    int q0 = blockIdx.x * 64, d0 = blockIdx.y * 64, b = blockIdx.z;
    int c = threadIdx.x & 63;
    int r4 = threadIdx.x >> 6;
#pragma unroll
    for (int i = 0; i < 16; ++i) {
        int r = r4 + i * 4;  // q row
        tile[r][c] = Q[(b * 2048 + q0 + r) * 256 + d0 + c];  // coalesced read
    }
    __syncthreads();
#pragma unroll
    for (int i = 0; i < 16; ++i) {
        int d = r4 + i * 4;
        VaT[(b * 256 + d0 + d) * 2048 + q0 + c] = f2bf(tile[c][d]);  // coalesced write
    }
    if (blockIdx.y == 0 && threadIdx.x < 64) {
        int qq = b * 2048 + q0 + threadIdx.x;
        maskadd[qq] = (qmask[qq] > 0) ? 0.f : NEG_BIG;
    }
}

// ---------------- flash attention: 4 waves x 16 rows, BQ=64 ----------------
__global__ __launch_bounds__(256) void k_attn(const short* __restrict__ Qa,
                                              const short* __restrict__ Ka,
                                              const short* __restrict__ VaT,
                                              const float* __restrict__ maskadd,
                                              float* __restrict__ out) {
    __shared__ __align__(16) short KaS[64 * 136];   // 64 rows x 128, pad->136
    __shared__ __align__(16) short VaS[256 * 72];   // 256 d-rows x 64, pad->72
    __shared__ __align__(16) short PS[4 * 16 * 72]; // per-wave P tile 16x64, pad->72
    __shared__ float maskS[64];

    int b = blockIdx.x & 7;                 // XCD-aware: batch per XCD
    int c0 = (blockIdx.x >> 3) * 64;
    int tid = threadIdx.x;
    int w = tid >> 6, lane = tid & 63, ln = lane & 15, qd = lane >> 4;

    // preload Q fragments for this wave's 16 rows (K=128 -> 4 frags)
    v8s qf[4];
    {
        const short* qp = Qa + (b * 2048 + c0 + w * 16 + ln) * 128 + qd * 8;
#pragma unroll
        for (int kk = 0; kk < 4; ++kk) qf[kk] = *(const v8s*)(qp + kk * 32);
    }

    v4f zero = {0.f, 0.f, 0.f, 0.f};
    v4f o[16];
#pragma unroll
    for (int i = 0; i < 16; ++i) o[i] = zero;
    float mrow[4] = {0.f, 0.f, 0.f, 0.f};   // init 0 (not -inf): masked-only tiles safe
    float lrow[4] = {0.f, 0.f, 0.f, 0.f};

    short* PSw = PS + w * (16 * 72);
    const short* kbase = Ka + (b * 2048) * 128;
    const short* vbase = VaT + (b * 256) * 2048;

    for (int q0 = 0; q0 < 2048; q0 += 64) {
        __syncthreads();
        // stage Ka tile: 64 rows x 128 shorts = 1024 int4 chunks
#pragma unroll
        for (int i = 0; i < 4; ++i) {
            int id = tid + i * 256;
            int r = id >> 4, c16 = id & 15;
            *(int4*)(KaS + r * 136 + c16 * 8) =
                *(const int4*)(kbase + (q0 + r) * 128 + c16 * 8);
        }
        // stage Va tile: 256 d-rows x 64 shorts = 2048 int4 chunks
#pragma unroll
        for (int i = 0; i < 8; ++i) {
            int id = tid + i * 256;
            int d = id >> 3, c16 = id & 7;
            *(int4*)(VaS + d * 72 + c16 * 8) =
                *(const int4*)(vbase + d * 2048 + q0 + c16 * 8);
        }
        if (tid < 64) maskS[tid] = maskadd[b * 2048 + q0 + tid];
        __syncthreads();

        // S = Qa @ Ka^T  (16 rows x 64 cols per wave)
        v4f s[4];
#pragma unroll
        for (int nt = 0; nt < 4; ++nt) {
            s[nt] = zero;
#pragma unroll
            for (int kk = 0; kk < 4; ++kk) {
                v8s kf = *(const v8s*)(KaS + (nt * 16 + ln) * 136 + kk * 32 + qd * 8);
                s[nt] = __builtin_amdgcn_mfma_f32_16x16x32_bf16(qf[kk], kf, s[nt], 0, 0, 0);
            }
        }

        // scale + query mask (additive -1e30 absorbs) + diagonal mask
        float mk[4];
#pragma unroll
        for (int nt = 0; nt < 4; ++nt) mk[nt] = maskS[nt * 16 + ln];
#pragma unroll
        for (int nt = 0; nt < 4; ++nt)
#pragma unroll
            for (int r = 0; r < 4; ++r)
                s[nt][r] = s[nt][r] * INV_SCALE + mk[nt];
        if (q0 == c0) {           // diagonal only possible when tiles align
            int crow = w * 16 + qd * 4;
#pragma unroll
            for (int nt = 0; nt < 4; ++nt)
#pragma unroll
                for (int r = 0; r < 4; ++r)
                    if (crow + r == nt * 16 + ln) s[nt][r] = NEG_BIG;
        }

        // online softmax: row max across 16 lanes (same qd group)
        float mnew[4], alpha[4];
#pragma unroll
        for (int r = 0; r < 4; ++r) {
            float tm = fmaxf(fmaxf(s[0][r], s[1][r]), fmaxf(s[2][r], s[3][r]));
            tm = fmaxf(tm, __shfl_xor(tm, 1));
            tm = fmaxf(tm, __shfl_xor(tm, 2));
            tm = fmaxf(tm, __shfl_xor(tm, 4));
            tm = fmaxf(tm, __shfl_xor(tm, 8));
            mnew[r] = fmaxf(mrow[r], tm);
            alpha[r] = exp2f((mrow[r] - mnew[r]) * L2E);
            mrow[r] = mnew[r];
        }
#pragma unroll
        for (int nt = 0; nt < 4; ++nt)
#pragma unroll
            for (int r = 0; r < 4; ++r)
                s[nt][r] = exp2f((s[nt][r] - mnew[r]) * L2E);
        // row sums -> l update
#pragma unroll
        for (int r = 0; r < 4; ++r) {
            float rs = s[0][r] + s[1][r] + s[2][r] + s[3][r];
            rs += __shfl_xor(rs, 1);
            rs += __shfl_xor(rs, 2);
            rs += __shfl_xor(rs, 4);
            rs += __shfl_xor(rs, 8);
            lrow[r] = lrow[r] * alpha[r] + rs;
        }
        // rescale O only if some alpha < 1 (m changed)
        int need = (alpha[0] < 1.f) | (alpha[1] < 1.f) | (alpha[2] < 1.f) | (alpha[3] < 1.f);
        if (__any(need)) {
#pragma unroll
            for (int i = 0; i < 16; ++i)
#pragma unroll
                for (int r = 0; r < 4; ++r) o[i][r] *= alpha[r];
        }
        // P -> LDS (C-layout -> A-layout round trip), wave-private, no barrier
#pragma unroll
        for (int nt = 0; nt < 4; ++nt)
#pragma unroll
            for (int r = 0; r < 4; ++r)
                PSw[(qd * 4 + r) * 72 + nt * 16 + ln] = f2bf(s[nt][r]);
        // O += P @ Va   (16 x 256, K=64)
#pragma unroll
        for (int kk2 = 0; kk2 < 2; ++kk2) {
            v8s pf = *(const v8s*)(PSw + ln * 72 + kk2 * 32 + qd * 8);
#pragma unroll
            for (int nt2 = 0; nt2 < 16; ++nt2) {
                v8s vf = *(const v8s*)(VaS + (nt2 * 16 + ln) * 72 + kk2 * 32 + qd * 8);
                o[nt2] = __builtin_amdgcn_mfma_f32_16x16x32_bf16(pf, vf, o[nt2], 0, 0, 0);
            }
        }
    }

    // epilogue: divide by l, store f32
    float inv_l[4];
#pragma unroll
    for (int r = 0; r < 4; ++r) inv_l[r] = 1.f / lrow[r];
#pragma unroll
    for (int nt2 = 0; nt2 < 16; ++nt2)
#pragma unroll
        for (int r = 0; r < 4; ++r)
            out[(b * 2048 + c0 + w * 16 + qd * 4 + r) * 256 + nt2 * 16 + ln] =
                o[nt2][r] * inv_l[r];
}

extern "C" void kernel_launch(void* const* d_in, const int* in_sizes, int n_in,
                              void* d_out, int out_size, void* d_ws, size_t ws_size,
                              hipStream_t stream) {
    const float* ctx  = (const float*)d_in[0];
    const float* qry  = (const float*)d_in[1];
    const float* win  = (const float*)d_in[2];
    const float* wmem = (const float*)d_in[3];
    const int* qmask  = (const int*)d_in[4];
    float* out = (float*)d_out;

    char* ws = (char*)d_ws;
    short* Qa      = (short*)(ws);                         // 4 MB
    short* Ka      = (short*)(ws + (4u << 20));            // 4 MB
    short* VaT     = (short*)(ws + (8u << 20));            // 8 MB
    float* maskadd = (float*)(ws + (16u << 20));           // 64 KB
    short* WtIn    = (short*)(ws + (16u << 20) + 65536);   // 64 KB
    short* WtMem   = (short*)(ws + (16u << 20) + 131072);  // 64 KB

    k_wt<<<dim3(32, 2), 256, 0, stream>>>(win, wmem, WtIn, WtMem);
    k_gemm_elu<<<dim3(256, 2), 256, 0, stream>>>(ctx, qry, WtIn, WtMem, Qa, Ka);
    k_vat<<<dim3(32, 4, 8), 256, 0, stream>>>(qry, qmask, VaT, maskadd);
    k_attn<<<dim3(256), 256, 0, stream>>>(Qa, Ka, VaT, maskadd, out);
}

// Round 3
// 215.226 us; speedup vs baseline: 1.3675x; 1.3675x over previous
//
#include <hip/hip_runtime.h>
#include <math.h>

typedef short v8s __attribute__((ext_vector_type(8)));
typedef float v4f __attribute__((ext_vector_type(4)));

#define L2E 1.4426950408889634f
#define INV_SCALE 0.08838834764831845f   // 1/sqrt(128)
#define NEG_BIG -1e30f

static __device__ __forceinline__ short f2bf(float x) {
    union { float f; unsigned u; } c; c.f = x;
    unsigned u = c.u;
    unsigned r = (u + 0x7fffu + ((u >> 16) & 1u)) >> 16;  // RNE
    return (short)r;
}

// ---------------- P0: W[256][128] f32 -> Wt[128][256] bf16 ----------------
__global__ __launch_bounds__(256) void k_wt(const float* __restrict__ Win,
                                            const float* __restrict__ Wmem,
                                            short* __restrict__ WtIn,
                                            short* __restrict__ WtMem) {
    const float* W = blockIdx.y ? Wmem : Win;
    short* Wt = blockIdx.y ? WtMem : WtIn;
    int id0 = blockIdx.x * 1024;
#pragma unroll
    for (int i = 0; i < 4; ++i) {
        int id = id0 + i * 256 + threadIdx.x;   // id = f*256 + k
        int f = id >> 8, k = id & 255;
        Wt[id] = f2bf(W[k * 128 + f]);          // coalesced writes
    }
}

// -------- P1: Y[m][128] = bf16(ELU(X[m][256] @ W)), MFMA 16x16x32 ---------
__global__ __launch_bounds__(256) void k_gemm_elu(const float* __restrict__ Xc,
                                                  const float* __restrict__ Xq,
                                                  const short* __restrict__ WtIn,
                                                  const short* __restrict__ WtMem,
                                                  short* __restrict__ Qa,
                                                  short* __restrict__ Ka) {
    const float* X = blockIdx.y ? Xq : Xc;
    const short* Wt = blockIdx.y ? WtMem : WtIn;
    short* Y = blockIdx.y ? Ka : Qa;
    int w = threadIdx.x >> 6, lane = threadIdx.x & 63;
    int ln = lane & 15, qd = lane >> 4;
    int m0 = blockIdx.x * 64 + w * 16;

    v4f zero = {0.f, 0.f, 0.f, 0.f};
    v4f o[8];
#pragma unroll
    for (int i = 0; i < 8; ++i) o[i] = zero;

#pragma unroll
    for (int kk = 0; kk < 8; ++kk) {
        const float* xp = X + (m0 + ln) * 256 + kk * 32 + qd * 8;
        float4 x0 = *(const float4*)xp;
        float4 x1 = *(const float4*)(xp + 4);
        v8s a;
        a[0] = f2bf(x0.x); a[1] = f2bf(x0.y); a[2] = f2bf(x0.z); a[3] = f2bf(x0.w);
        a[4] = f2bf(x1.x); a[5] = f2bf(x1.y); a[6] = f2bf(x1.z); a[7] = f2bf(x1.w);
#pragma unroll
        for (int nt = 0; nt < 8; ++nt) {
            v8s b = *(const v8s*)(Wt + (nt * 16 + ln) * 256 + kk * 32 + qd * 8);
            o[nt] = __builtin_amdgcn_mfma_f32_16x16x32_bf16(a, b, o[nt], 0, 0, 0);
        }
    }
#pragma unroll
    for (int nt = 0; nt < 8; ++nt) {
#pragma unroll
        for (int r = 0; r < 4; ++r) {
            float v = o[nt][r];
            v = v > 0.f ? v : 0.01f * (__expf(v) - 1.f);
            Y[(m0 + qd * 4 + r) * 128 + nt * 16 + ln] = f2bf(v);
        }
    }
}

// ------ P2: Va_t[b][d][q] = bf16(query[b][q][d]); maskadd from qmask ------
__global__ __launch_bounds__(256) void k_vat(const float* __restrict__ Q,
                                             const int* __restrict__ qmask,
                                             short* __restrict__ VaT,
                                             float* __restrict__ maskadd) {
    __shared__ float tile[64][65];
    int q0 = blockIdx.x * 64, d0 = blockIdx.y * 64, b = blockIdx.z;
    int c = threadIdx.x & 63;
    int r4 = threadIdx.x >> 6;
#pragma unroll
    for (int i = 0; i < 16; ++i) {
        int r = r4 + i * 4;
        tile[r][c] = Q[(b * 2048 + q0 + r) * 256 + d0 + c];
    }
    __syncthreads();
#pragma unroll
    for (int i = 0; i < 16; ++i) {
        int d = r4 + i * 4;
        VaT[(b * 256 + d0 + d) * 2048 + q0 + c] = f2bf(tile[c][d]);
    }
    if (blockIdx.y == 0 && threadIdx.x < 64) {
        int qq = b * 2048 + q0 + threadIdx.x;
        maskadd[qq] = (qmask[qq] > 0) ? 0.f : NEG_BIG;
    }
}

// -------- flash attention, BQ=64 (4 waves x 16 rows), BK=32, KV-split -----
// NSPLIT-way split over the kv axis; partials (unnormalized O, m, l) go to
// Opart/ml; DIRECT=true writes normalized output directly (NSPLIT must be 1).
// LDS = 34.4 KB -> 4 blocks/CU; launch_bounds(256,4) caps VGPR at 128.
template<int NSPLIT, bool DIRECT>
__global__ __launch_bounds__(256, 4) void k_attn(const short* __restrict__ Qa,
                                                 const short* __restrict__ Ka,
                                                 const short* __restrict__ VaT,
                                                 const float* __restrict__ maskadd,
                                                 float* __restrict__ Opart,
                                                 float2* __restrict__ ml,
                                                 float* __restrict__ out) {
    __shared__ __align__(16) short KaS[32 * 136];   // 32 kv-rows x 128, pad->136
    __shared__ __align__(16) short VaS[256 * 40];   // 256 d-rows x 32, pad->40
    __shared__ __align__(16) short PS[4 * 16 * 40]; // per-wave P tile 16x32
    __shared__ float maskS[32];

    int blk = blockIdx.x;
    int b = blk & 7;                        // batch per XCD: K+V = 1.5MB fits L2
    int t = blk >> 3;
    int c0 = (t & 31) * 64;
    int sp = t >> 5;
    const int KVLEN = 2048 / NSPLIT;
    int kv0 = sp * KVLEN;

    int tid = threadIdx.x;
    int w = tid >> 6, lane = tid & 63, ln = lane & 15, qd = lane >> 4;

    v8s qf[4];
    {
        const short* qp = Qa + (b * 2048 + c0 + w * 16 + ln) * 128 + qd * 8;
#pragma unroll
        for (int kk = 0; kk < 4; ++kk) qf[kk] = *(const v8s*)(qp + kk * 32);
    }

    v4f zero = {0.f, 0.f, 0.f, 0.f};
    v4f o[16];
#pragma unroll
    for (int i = 0; i < 16; ++i) o[i] = zero;
    float mrow[4] = {0.f, 0.f, 0.f, 0.f};   // m init 0: safe (max-overestimate)
    float lrow[4] = {0.f, 0.f, 0.f, 0.f};

    short* PSw = PS + w * (16 * 40);
    const short* kbase = Ka + (b * 2048) * 128;
    const short* vbase = VaT + (b * 256) * 2048;
    int grow = c0 + w * 16 + qd * 4;        // global c-row of o[.][r=0]

    for (int q0 = kv0; q0 < kv0 + KVLEN; q0 += 32) {
        __syncthreads();
        // stage Ka tile: 32 rows x 128 shorts = 512 int4 chunks
#pragma unroll
        for (int i = 0; i < 2; ++i) {
            int id = tid + i * 256;
            int r = id >> 4, c16 = id & 15;
            *(int4*)(KaS + r * 136 + c16 * 8) =
                *(const int4*)(kbase + (q0 + r) * 128 + c16 * 8);
        }
        // stage Va tile: 256 d-rows x 32 shorts = 1024 int4 chunks
#pragma unroll
        for (int i = 0; i < 4; ++i) {
            int id = tid + i * 256;
            int d = id >> 2, c16 = id & 3;
            *(int4*)(VaS + d * 40 + c16 * 8) =
                *(const int4*)(vbase + d * 2048 + q0 + c16 * 8);
        }
        if (tid < 32) maskS[tid] = maskadd[b * 2048 + q0 + tid];
        __syncthreads();

        // S = Qa @ Ka^T  (16 rows x 32 cols per wave)
        v4f s[2];
#pragma unroll
        for (int nt = 0; nt < 2; ++nt) {
            s[nt] = zero;
#pragma unroll
            for (int kk = 0; kk < 4; ++kk) {
                v8s kf = *(const v8s*)(KaS + (nt * 16 + ln) * 136 + kk * 32 + qd * 8);
                s[nt] = __builtin_amdgcn_mfma_f32_16x16x32_bf16(qf[kk], kf, s[nt], 0, 0, 0);
            }
        }

        // scale + query mask + diagonal
#pragma unroll
        for (int nt = 0; nt < 2; ++nt) {
            float mk = maskS[nt * 16 + ln];
            int kcol = q0 + nt * 16 + ln;   // global kv index of this lane's col
#pragma unroll
            for (int r = 0; r < 4; ++r) {
                float v = s[nt][r] * INV_SCALE + mk;
                s[nt][r] = (kcol == grow + r) ? NEG_BIG : v;
            }
        }

        // online softmax: row reduce over 32 cols (2 tiles x 16 ln-lanes)
        float mnew[4], alpha[4];
#pragma unroll
        for (int r = 0; r < 4; ++r) {
            float tm = fmaxf(s[0][r], s[1][r]);
            tm = fmaxf(tm, __shfl_xor(tm, 1));
            tm = fmaxf(tm, __shfl_xor(tm, 2));
            tm = fmaxf(tm, __shfl_xor(tm, 4));
            tm = fmaxf(tm, __shfl_xor(tm, 8));
            mnew[r] = fmaxf(mrow[r], tm);
            alpha[r] = exp2f((mrow[r] - mnew[r]) * L2E);
            mrow[r] = mnew[r];
        }
#pragma unroll
        for (int nt = 0; nt < 2; ++nt)
#pragma unroll
            for (int r = 0; r < 4; ++r)
                s[nt][r] = exp2f((s[nt][r] - mnew[r]) * L2E);
#pragma unroll
        for (int r = 0; r < 4; ++r) {
            float rs = s[0][r] + s[1][r];
            rs += __shfl_xor(rs, 1);
            rs += __shfl_xor(rs, 2);
            rs += __shfl_xor(rs, 4);
            rs += __shfl_xor(rs, 8);
            lrow[r] = lrow[r] * alpha[r] + rs;
        }
        int need = (alpha[0] < 1.f) | (alpha[1] < 1.f) | (alpha[2] < 1.f) | (alpha[3] < 1.f);
        if (__any(need)) {
#pragma unroll
            for (int i = 0; i < 16; ++i)
#pragma unroll
                for (int r = 0; r < 4; ++r) o[i][r] *= alpha[r];
        }
        // P -> LDS round trip (wave-private)
#pragma unroll
        for (int nt = 0; nt < 2; ++nt)
#pragma unroll
            for (int r = 0; r < 4; ++r)
                PSw[(qd * 4 + r) * 40 + nt * 16 + ln] = f2bf(s[nt][r]);
        // O += P @ Va   (16 x 256, K=32)
        v8s pf = *(const v8s*)(PSw + ln * 40 + qd * 8);
#pragma unroll
        for (int nt2 = 0; nt2 < 16; ++nt2) {
            v8s vf = *(const v8s*)(VaS + (nt2 * 16 + ln) * 40 + qd * 8);
            o[nt2] = __builtin_amdgcn_mfma_f32_16x16x32_bf16(pf, vf, o[nt2], 0, 0, 0);
        }
    }

    if (DIRECT) {
        float inv_l[4];
#pragma unroll
        for (int r = 0; r < 4; ++r) inv_l[r] = 1.f / lrow[r];
#pragma unroll
        for (int nt2 = 0; nt2 < 16; ++nt2)
#pragma unroll
            for (int r = 0; r < 4; ++r)
                out[(b * 2048 + grow + r) * 256 + nt2 * 16 + ln] = o[nt2][r] * inv_l[r];
    } else {
        int rowg = b * 2048 + grow;         // global row (0..16383)
        float* op = Opart + (size_t)sp * (16384 * 256);
#pragma unroll
        for (int nt2 = 0; nt2 < 16; ++nt2)
#pragma unroll
            for (int r = 0; r < 4; ++r)
                op[(rowg + r) * 256 + nt2 * 16 + ln] = o[nt2][r];
        if (ln == 0) {
#pragma unroll
            for (int r = 0; r < 4; ++r)
                ml[sp * 16384 + rowg + r] = make_float2(mrow[r], lrow[r]);
        }
    }
}

// ---------------- combine partials across NSPLIT kv-splits ----------------
template<int NSPLIT>
__global__ __launch_bounds__(256) void k_combine(const float* __restrict__ Opart,
                                                 const float2* __restrict__ ml,
                                                 float* __restrict__ out) {
    int idx = blockIdx.x * 256 + threadIdx.x;    // 16384 rows x 64 float4s
    int row = idx >> 6, d4 = (idx & 63) * 4;
    float m[NSPLIT], l[NSPLIT], M = -1e30f;
#pragma unroll
    for (int s = 0; s < NSPLIT; ++s) {
        float2 v = ml[s * 16384 + row];
        m[s] = v.x; l[s] = v.y;
        M = fmaxf(M, m[s]);
    }
    float L = 0.f;
    float4 acc = {0.f, 0.f, 0.f, 0.f};
#pragma unroll
    for (int s = 0; s < NSPLIT; ++s) {
        float wgt = exp2f((m[s] - M) * L2E);
        L += wgt * l[s];
        float4 v = *(const float4*)(Opart + (size_t)s * (16384 * 256) + row * 256 + d4);
        acc.x += wgt * v.x; acc.y += wgt * v.y;
        acc.z += wgt * v.z; acc.w += wgt * v.w;
    }
    float inv = 1.f / L;
    float4 res = {acc.x * inv, acc.y * inv, acc.z * inv, acc.w * inv};
    *(float4*)(out + row * 256 + d4) = res;
}

extern "C" void kernel_launch(void* const* d_in, const int* in_sizes, int n_in,
                              void* d_out, int out_size, void* d_ws, size_t ws_size,
                              hipStream_t stream) {
    const float* ctx  = (const float*)d_in[0];
    const float* qry  = (const float*)d_in[1];
    const float* win  = (const float*)d_in[2];
    const float* wmem = (const float*)d_in[3];
    const int* qmask  = (const int*)d_in[4];
    float* out = (float*)d_out;

    char* ws = (char*)d_ws;
    short* Qa      = (short*)(ws);                          // 4 MB
    short* Ka      = (short*)(ws + (4u << 20));             // 4 MB
    short* VaT     = (short*)(ws + (8u << 20));             // 8 MB
    float* maskadd = (float*)(ws + (16u << 20));            // 64 KB
    short* WtIn    = (short*)(ws + (16u << 20) + 65536);    // 64 KB
    short* WtMem   = (short*)(ws + (16u << 20) + 131072);   // 64 KB
    float2* ml     = (float2*)(ws + (16u << 20) + 196608);  // up to 512 KB
    float* Opart   = (float*)(ws + (18u << 20));            // NSPLIT x 16 MB

    k_wt<<<dim3(32, 2), 256, 0, stream>>>(win, wmem, WtIn, WtMem);
    k_gemm_elu<<<dim3(256, 2), 256, 0, stream>>>(ctx, qry, WtIn, WtMem, Qa, Ka);
    k_vat<<<dim3(32, 4, 8), 256, 0, stream>>>(qry, qmask, VaT, maskadd);

    const size_t base = 18u << 20, part = 16u << 20;
    if (ws_size >= base + 4 * part) {
        k_attn<4, false><<<dim3(8 * 32 * 4), 256, 0, stream>>>(Qa, Ka, VaT, maskadd, Opart, ml, out);
        k_combine<4><<<dim3(4096), 256, 0, stream>>>(Opart, ml, out);
    } else if (ws_size >= base + 2 * part) {
        k_attn<2, false><<<dim3(8 * 32 * 2), 256, 0, stream>>>(Qa, Ka, VaT, maskadd, Opart, ml, out);
        k_combine<2><<<dim3(4096), 256, 0, stream>>>(Opart, ml, out);
    } else {
        k_attn<1, true><<<dim3(8 * 32), 256, 0, stream>>>(Qa, Ka, VaT, maskadd, Opart, ml, out);
    }
}